// Round 5
// baseline (29.189 us; speedup 1.0000x reference)
//
#include <hip/hip_runtime.h>
#include <math.h>

// OSDT split into two phase-pure kernels:
//  K1 (read-bound): logits z[b,d] = (x[b].w[d] - thr[d]) * exp(-lt[d])
//      33.6 MB read, 0.65 MB write  -> ~5.5-6.5 us at read peak
//  K2 (write-bound, fill-like): out[b,l] = prod_d (bit_d(l) ? sig(z) : sig(-z))
//      0.65 MB read (L2/L3-hit), 67 MB write -> ~10-10.5 us at fill rate
// Monolithic version exposed ~4 us of DS+compute at the read->write seam;
// the split lets each phase run at its own BW ceiling.

#define IDIM   512
#define DEPTH  10
#define NLEAF  1024

// ---------------------------------------------------------------------------
// K1: 16-lane subgroup per row pair; 2 rows per thread share each weight
// fragment (halves DS-pipe traffic to ~2.1 us/CU, inside the read window).
// 32 rows per 256-thread block.
__global__ __launch_bounds__(256, 4) void osdt_logits(
    const float* __restrict__ x,
    const float* __restrict__ sw,
    const float* __restrict__ thr,
    const float* __restrict__ lt,
    float* __restrict__ z, int zstride, int batch)
{
    __shared__ float4 s_w4[DEPTH * IDIM / 4];   // 20 KiB

    const int lane = threadIdx.x & 63;
    const int wave = threadIdx.x >> 6;
    const int g    = lane & 15;                 // lane within subgroup
    const int sg   = lane >> 4;                 // subgroup 0..3
    const int rowA = blockIdx.x * 32 + wave * 8 + sg * 2;
    const int rowB = rowA + 1;                  // batch % 32 == 0 (B=16384)
    if (rowA >= batch) return;

    // Issue all 16 x-loads up-front (256B-contiguous per subgroup chunk).
    float4 xa[8], xb[8];
    {
        const float4* xrA = reinterpret_cast<const float4*>(x + (size_t)rowA * IDIM);
        const float4* xrB = reinterpret_cast<const float4*>(x + (size_t)rowB * IDIM);
        #pragma unroll
        for (int c = 0; c < 8; ++c) { xa[c] = xrA[c * 16 + g]; xb[c] = xrB[c * 16 + g]; }
    }

    // Stage the 20 KiB weight matrix into LDS (overlaps with x loads).
    {
        const float4* src = reinterpret_cast<const float4*>(sw);
        #pragma unroll
        for (int i = 0; i < 5; ++i)
            s_w4[threadIdx.x + i * 256] = src[threadIdx.x + i * 256];
    }
    __syncthreads();

    // Per-depth partial dots; each weight float4 feeds BOTH rows.
    float pa[DEPTH], pb[DEPTH];
    #pragma unroll
    for (int d = 0; d < DEPTH; ++d) {
        float sa = 0.0f, sb = 0.0f;
        #pragma unroll
        for (int c = 0; c < 8; ++c) {
            const float4 w = s_w4[d * 128 + c * 16 + g];
            sa += xa[c].x * w.x + xa[c].y * w.y + xa[c].z * w.z + xa[c].w * w.w;
            sb += xb[c].x * w.x + xb[c].y * w.y + xb[c].z * w.z + xb[c].w * w.w;
        }
        pa[d] = sa; pb[d] = sb;
    }

    // 4-step butterfly within the 16-lane subgroup (masks 1/2/4/8, DPP-able).
    #pragma unroll
    for (int d = 0; d < DEPTH; ++d) {
        #pragma unroll
        for (int m = 1; m < 16; m <<= 1) {
            pa[d] += __shfl_xor(pa[d], m, 64);
            pb[d] += __shfl_xor(pb[d], m, 64);
        }
    }

    // Lane g (< 10) stores depth g. Static cndmask chain, no runtime
    // register indexing (avoids scratch).
    if (g < DEPTH) {
        float va = pa[0], vb = pb[0];
        #pragma unroll
        for (int d = 1; d < DEPTH; ++d)
            if (g == d) { va = pa[d]; vb = pb[d]; }
        const float s = __expf(-lt[g]);
        const float t = thr[g];
        z[(size_t)rowA * zstride + g] = (va - t) * s;
        z[(size_t)rowB * zstride + g] = (vb - t) * s;
    }
}

// ---------------------------------------------------------------------------
// K2: one wave per row; fill-like writer. z may alias out (zstride==NLEAF
// fallback embeds z at the head of each row; same wave reads z before
// overwriting it, so no restrict on these params).
__global__ __launch_bounds__(256, 8) void osdt_leaves(
    const float* z, int zstride, float* out, int batch)
{
    const int lane = threadIdx.x & 63;
    const int wave = threadIdx.x >> 6;
    const int row  = blockIdx.x * 4 + wave;
    if (row >= batch) return;

    // Wave-uniform 40B read (L2/L3-resident; broadcast within the wave).
    const float* zr = z + (size_t)row * zstride;
    float lv[DEPTH], rv[DEPTH];
    #pragma unroll
    for (int d = 0; d < DEPTH; ++d) {
        // Clamp |zz|<=30: |dot| reaches ~100 and expf overflows to inf
        // (inf*0 = NaN). sigmoid(30)=1-9e-14 << 2e-2 tolerance.
        float zz = fminf(fmaxf(zr[d], -30.0f), 30.0f);
        const float e = __expf(-zz);
        const float r = 1.0f / (1.0f + e);      // sigmoid(z)
        rv[d] = r;
        lv[d] = e * r;                          // sigmoid(-z)
    }

    // Leaf l = j*256 + lane*4 + k: bits0-1=k -> d0,d1; bits2-7=lane -> d2..d7;
    // bits8-9=j -> d8,d9.
    const float base =
        ((lane &  1) ? rv[2] : lv[2]) * ((lane &  2) ? rv[3] : lv[3]) *
        ((lane &  4) ? rv[4] : lv[4]) * ((lane &  8) ? rv[5] : lv[5]) *
        ((lane & 16) ? rv[6] : lv[6]) * ((lane & 32) ? rv[7] : lv[7]);
    float hb[4];
    hb[0] = lv[0] * lv[1] * base;  hb[1] = rv[0] * lv[1] * base;
    hb[2] = lv[0] * rv[1] * base;  hb[3] = rv[0] * rv[1] * base;
    const float t89[4] = { lv[8] * lv[9], rv[8] * lv[9],
                           lv[8] * rv[9], rv[8] * rv[9] };

    float* orow = out + (size_t)row * NLEAF;
    #pragma unroll
    for (int j = 0; j < 4; ++j) {
        float4 v;
        v.x = hb[0] * t89[j];
        v.y = hb[1] * t89[j];
        v.z = hb[2] * t89[j];
        v.w = hb[3] * t89[j];
        *reinterpret_cast<float4*>(orow + j * 256 + lane * 4) = v;
    }
}

extern "C" void kernel_launch(void* const* d_in, const int* in_sizes, int n_in,
                              void* d_out, int out_size, void* d_ws, size_t ws_size,
                              hipStream_t stream) {
    const float* x   = (const float*)d_in[0];
    const float* sw  = (const float*)d_in[1];
    const float* thr = (const float*)d_in[2];
    const float* lt  = (const float*)d_in[3];
    float* out = (float*)d_out;

    const int batch = in_sizes[0] / IDIM;                 // 16384

    // z buffer: workspace if big enough, else embed at head of each out row
    // (race-free: the K2 wave that overwrites row r is the one that read z[r]).
    float* zbuf;
    int zstride;
    if (ws_size >= (size_t)batch * DEPTH * sizeof(float)) {
        zbuf = (float*)d_ws;  zstride = DEPTH;
    } else {
        zbuf = out;           zstride = NLEAF;
    }

    const int blocks1 = (batch + 31) / 32;                // 512
    osdt_logits<<<blocks1, 256, 0, stream>>>(x, sw, thr, lt, zbuf, zstride, batch);

    const int blocks2 = (batch + 3) / 4;                  // 4096
    osdt_leaves<<<blocks2, 256, 0, stream>>>(zbuf, zstride, out, batch);
}

// Round 6
// 22.812 us; speedup vs baseline: 1.2796x; 1.2796x over previous
//
#include <hip/hip_runtime.h>
#include <math.h>

// OSDT: soft decision tree leaf probabilities (monolithic, round-3 structure
// + 2-rows-per-thread weight sharing).
// x:[B,512] f32, w:[10,512] f32, thr:[10], lt:[10]  ->  out:[B,1024] f32
// Memory-bound: 33.6 MB read + 67 MB write => ~16 us floor at 6.3 TB/s.
//
// Round-4 lesson: kernel split serializes the HBM phases -> 29 us. Monolithic
// overlap wins. Round-3 gap analysis: 20 ds_read_b128 per row (5.3 us/CU) was
// the exposed non-bus cost. Here each 16-lane subgroup computes TWO rows, so
// every weight fragment read from LDS feeds both rows: 5 reads/row (~1.3
// us/CU). Butterfly stays 4 steps; x loads (16 float4) all issued up-front.

#define IDIM   512
#define DEPTH  10
#define NLEAF  1024

__global__ __launch_bounds__(256, 2) void osdt_kernel(
    const float* __restrict__ x,
    const float* __restrict__ sw,
    const float* __restrict__ thr,
    const float* __restrict__ lt,
    float* __restrict__ out,
    int batch)
{
    __shared__ float4 s_w4[DEPTH * IDIM / 4];   // 1280 float4 = 20 KiB

    const int lane = threadIdx.x & 63;
    const int wave = threadIdx.x >> 6;
    const int g    = lane & 15;                 // lane within subgroup
    const int sg   = lane >> 4;                 // subgroup 0..3
    // Each subgroup owns rows (rowA, rowA+1); 8 rows/wave, 32 rows/block.
    const int rowA = blockIdx.x * 32 + wave * 8 + sg * 2;
    if (rowA >= batch) return;
    const int rowB = rowA + 1;                  // batch % 32 == 0 (B=16384)

    // Issue all 16 x-loads up-front (256B-contiguous per subgroup chunk);
    // they fly while we stage the weights.
    float4 xa[8], xb[8];
    {
        const float4* xrA = reinterpret_cast<const float4*>(x + (size_t)rowA * IDIM);
        const float4* xrB = reinterpret_cast<const float4*>(x + (size_t)rowB * IDIM);
        #pragma unroll
        for (int c = 0; c < 8; ++c) xa[c] = xrA[c * 16 + g];
        #pragma unroll
        for (int c = 0; c < 8; ++c) xb[c] = xrB[c * 16 + g];
    }

    // Stage the 20 KiB weight matrix into LDS (overlaps with x loads).
    {
        const float4* src = reinterpret_cast<const float4*>(sw);
        #pragma unroll
        for (int i = 0; i < 5; ++i)
            s_w4[threadIdx.x + i * 256] = src[threadIdx.x + i * 256];
    }
    float thrv[DEPTH], sclv[DEPTH];
    #pragma unroll
    for (int d = 0; d < DEPTH; ++d) {
        thrv[d] = thr[d];
        sclv[d] = __expf(-lt[d]);
    }
    __syncthreads();

    // Per-depth partial dots; every LDS weight fragment feeds BOTH rows.
    // (Subgroups 0..3 read identical addresses -> LDS broadcast, conflict-free.)
    float pa[DEPTH], pb[DEPTH];
    #pragma unroll
    for (int d = 0; d < DEPTH; ++d) {
        float sa = 0.0f, sb = 0.0f;
        #pragma unroll
        for (int c = 0; c < 8; ++c) {
            const float4 w = s_w4[d * 128 + c * 16 + g];
            sa += xa[c].x * w.x + xa[c].y * w.y + xa[c].z * w.z + xa[c].w * w.w;
            sb += xb[c].x * w.x + xb[c].y * w.y + xb[c].z * w.z + xb[c].w * w.w;
        }
        pa[d] = sa; pb[d] = sb;
    }

    // 4-step butterfly within the 16-lane subgroup (masks 1/2/4/8);
    // result broadcast to all 16 lanes.
    #pragma unroll
    for (int d = 0; d < DEPTH; ++d) {
        #pragma unroll
        for (int m = 1; m < 16; m <<= 1) {
            pa[d] += __shfl_xor(pa[d], m, 64);
            pb[d] += __shfl_xor(pb[d], m, 64);
        }
    }

    // ---- per-row epilogue: sigmoids + factored leaf products + 16 stores.
    // Clamp |z|<=30: |dot| can reach ~100 and expf overflows to inf
    // (inf*0 = NaN). sigmoid(30)=1-9e-14 << 2e-2 tolerance.
    #pragma unroll
    for (int r = 0; r < 2; ++r) {
        float lv[DEPTH], rv[DEPTH];
        #pragma unroll
        for (int d = 0; d < DEPTH; ++d) {
            float z = ((r ? pb[d] : pa[d]) - thrv[d]) * sclv[d];
            z = fminf(fmaxf(z, -30.0f), 30.0f);
            const float e  = __expf(-z);
            const float rr = 1.0f / (1.0f + e);   // sigmoid(z)
            rv[d] = rr;
            lv[d] = e * rr;                       // sigmoid(-z)
        }

        // Leaf l = c*64 + g*4 + k:
        //   bits 0,1 = k  -> depths 0,1 (head)
        //   bits 2..5 = g -> depths 2..5 (base, lane-specific)
        //   bits 6..9 = c -> depths 6..9 (t67 x t89)
        const float base =
            ((g & 1) ? rv[2] : lv[2]) * ((g & 2) ? rv[3] : lv[3]) *
            ((g & 4) ? rv[4] : lv[4]) * ((g & 8) ? rv[5] : lv[5]);
        float hb[4];
        hb[0] = lv[0] * lv[1] * base;  hb[1] = rv[0] * lv[1] * base;
        hb[2] = lv[0] * rv[1] * base;  hb[3] = rv[0] * rv[1] * base;
        float t67[4], t89[4];
        t67[0] = lv[6] * lv[7];  t67[1] = rv[6] * lv[7];
        t67[2] = lv[6] * rv[7];  t67[3] = rv[6] * rv[7];
        t89[0] = lv[8] * lv[9];  t89[1] = rv[8] * lv[9];
        t89[2] = lv[8] * rv[9];  t89[3] = rv[8] * rv[9];

        float* orow = out + (size_t)(r ? rowB : rowA) * NLEAF;
        #pragma unroll
        for (int c = 0; c < 16; ++c) {
            const float t = t67[c & 3] * t89[c >> 2];   // c compile-time
            float4 v;
            v.x = hb[0] * t;
            v.y = hb[1] * t;
            v.z = hb[2] * t;
            v.w = hb[3] * t;
            *reinterpret_cast<float4*>(orow + c * 64 + g * 4) = v;
        }
    }
}

extern "C" void kernel_launch(void* const* d_in, const int* in_sizes, int n_in,
                              void* d_out, int out_size, void* d_ws, size_t ws_size,
                              hipStream_t stream) {
    const float* x   = (const float*)d_in[0];
    const float* sw  = (const float*)d_in[1];
    const float* thr = (const float*)d_in[2];
    const float* lt  = (const float*)d_in[3];
    float* out = (float*)d_out;

    const int batch  = in_sizes[0] / IDIM;        // 16384
    const int blocks = (batch + 31) / 32;         // 512 (32 rows/block)

    osdt_kernel<<<blocks, 256, 0, stream>>>(x, sw, thr, lt, out, batch);
}

// Round 8
// 20.820 us; speedup vs baseline: 1.4020x; 1.0957x over previous
//
#include <hip/hip_runtime.h>
#include <math.h>

// OSDT: soft decision tree leaf probabilities (round-3 structure +
// non-temporal streaming hints).
// x:[B,512] f32, w:[10,512] f32, thr:[10], lt:[10]  ->  out:[B,1024] f32
// Memory-bound: 33.6 MB read + 67 MB write => ~15-16 us floor.
//
// R4 lesson: kernel split serializes HBM phases (29 us) — stay monolithic.
// R5 lesson: 2 rows/thread halves waves/CU and regresses (22.8 us) — keep
// 1 row per 16-lane subgroup, 16 waves/CU.
// R6/R7 change: out stores and x loads are non-temporal (no L2 allocation
// for the 67 MB write-once stream / 33.6 MB read-once stream). R7 fixes the
// compile error: __builtin_nontemporal_* needs a native clang vector type,
// not HIP_vector_type — use ext_vector_type(4) floats (same 16B layout).

#define IDIM   512
#define DEPTH  10
#define NLEAF  1024

typedef float f32x4 __attribute__((ext_vector_type(4)));

__global__ __launch_bounds__(256, 4) void osdt_kernel(
    const float* __restrict__ x,
    const float* __restrict__ sw,
    const float* __restrict__ thr,
    const float* __restrict__ lt,
    float* __restrict__ out,
    int batch)
{
    __shared__ float4 s_w4[DEPTH * IDIM / 4];   // 1280 float4 = 20 KiB

    const int lane = threadIdx.x & 63;
    const int wave = threadIdx.x >> 6;
    const int g    = lane & 15;                 // lane within subgroup
    const int sg   = lane >> 4;                 // subgroup 0..3
    const int row  = blockIdx.x * 16 + wave * 4 + sg;
    const int crow = row < batch ? row : batch - 1;   // clamped for loads

    // Issue all 8 x-loads first (32 elems/lane, non-temporal: read-once
    // stream, don't pollute L2). Subgroup reads 256B-contiguous segments.
    f32x4 xv[8];
    {
        const f32x4* xr = reinterpret_cast<const f32x4*>(x + (size_t)crow * IDIM);
        #pragma unroll
        for (int c = 0; c < 8; ++c)
            xv[c] = __builtin_nontemporal_load(&xr[c * 16 + g]);
    }

    // Stage the 20 KiB weight matrix into LDS (normal cached loads — reused
    // by all 1024 blocks; overlaps with the x loads).
    {
        const float4* src = reinterpret_cast<const float4*>(sw);
        #pragma unroll
        for (int i = 0; i < 5; ++i)
            s_w4[threadIdx.x + i * 256] = src[threadIdx.x + i * 256];
    }
    float thrv[DEPTH], sclv[DEPTH];
    #pragma unroll
    for (int d = 0; d < DEPTH; ++d) {
        thrv[d] = thr[d];
        sclv[d] = __expf(-lt[d]);
    }
    __syncthreads();

    // Per-depth partial dots: weights streamed from LDS (subgroups 0..3 read
    // identical addresses -> broadcast; 16 lanes x 16B = 2-way aliasing = free).
    float part[DEPTH];
    #pragma unroll
    for (int d = 0; d < DEPTH; ++d) {
        float a0 = 0.0f, a1 = 0.0f;
        #pragma unroll
        for (int c = 0; c < 8; c += 2) {
            const float4 w0 = s_w4[d * 128 + c * 16 + g];
            const float4 w1 = s_w4[d * 128 + (c + 1) * 16 + g];
            a0 += xv[c].x * w0.x + xv[c].y * w0.y +
                  xv[c].z * w0.z + xv[c].w * w0.w;
            a1 += xv[c + 1].x * w1.x + xv[c + 1].y * w1.y +
                  xv[c + 1].z * w1.z + xv[c + 1].w * w1.w;
        }
        part[d] = a0 + a1;
    }

    // 4-step butterfly within the 16-lane subgroup (masks 1/2/4/8);
    // result broadcast to all 16 lanes.
    #pragma unroll
    for (int d = 0; d < DEPTH; ++d) {
        #pragma unroll
        for (int m = 1; m < 16; m <<= 1)
            part[d] += __shfl_xor(part[d], m, 64);
    }

    // Sigmoids. Clamp |z|<=30: |dot| can reach ~100 and expf overflows to
    // inf (inf*0 = NaN). sigmoid(30)=1-9e-14 << 2e-2 tolerance.
    float lv[DEPTH], rv[DEPTH];
    #pragma unroll
    for (int d = 0; d < DEPTH; ++d) {
        float z = (part[d] - thrv[d]) * sclv[d];
        z = fminf(fmaxf(z, -30.0f), 30.0f);
        const float e  = __expf(-z);
        const float rr = 1.0f / (1.0f + e);   // sigmoid(z)
        rv[d] = rr;
        lv[d] = e * rr;                       // sigmoid(-z)
    }

    // Leaf l = c*64 + g*4 + k:
    //   bits 0,1 = k  -> depths 0,1 (head)
    //   bits 2..5 = g -> depths 2..5 (base, lane-specific)
    //   bits 6..9 = c -> depths 6..9 (t67 x t89)
    float base = ((g & 1) ? rv[2] : lv[2]) * ((g & 2) ? rv[3] : lv[3]) *
                 ((g & 4) ? rv[4] : lv[4]) * ((g & 8) ? rv[5] : lv[5]);
    float hb[4];
    hb[0] = lv[0] * lv[1] * base;  hb[1] = rv[0] * lv[1] * base;
    hb[2] = lv[0] * rv[1] * base;  hb[3] = rv[0] * rv[1] * base;
    float t67[4], t89[4];
    t67[0] = lv[6] * lv[7];  t67[1] = rv[6] * lv[7];
    t67[2] = lv[6] * rv[7];  t67[3] = rv[6] * rv[7];
    t89[0] = lv[8] * lv[9];  t89[1] = rv[8] * lv[9];
    t89[2] = lv[8] * rv[9];  t89[3] = rv[8] * rv[9];

    if (row >= batch) return;

    // 16 non-temporal float4 stores (output is written once, never re-read:
    // skip L2 allocation). Subgroup writes 256B-contiguous segments.
    float* orow = out + (size_t)row * NLEAF;
    #pragma unroll
    for (int c = 0; c < 16; ++c) {
        const float t = t67[c & 3] * t89[c >> 2];   // c compile-time
        f32x4 v;
        v.x = hb[0] * t;
        v.y = hb[1] * t;
        v.z = hb[2] * t;
        v.w = hb[3] * t;
        __builtin_nontemporal_store(
            v, reinterpret_cast<f32x4*>(orow + c * 64 + g * 4));
    }
}

extern "C" void kernel_launch(void* const* d_in, const int* in_sizes, int n_in,
                              void* d_out, int out_size, void* d_ws, size_t ws_size,
                              hipStream_t stream) {
    const float* x   = (const float*)d_in[0];
    const float* sw  = (const float*)d_in[1];
    const float* thr = (const float*)d_in[2];
    const float* lt  = (const float*)d_in[3];
    float* out = (float*)d_out;

    const int batch  = in_sizes[0] / IDIM;        // 16384
    const int blocks = (batch + 15) / 16;         // 1024 (16 rows/block)

    osdt_kernel<<<blocks, 256, 0, stream>>>(x, sw, thr, lt, out, batch);
}